// Round 2
// baseline (204.788 us; speedup 1.0000x reference)
//
#include <hip/hip_runtime.h>

// 5x5 normalized box blur, REFLECT_101, fp32, NCHW 32x3x512x512.
// Register-only separable blur: each thread owns one float4-column and a
// 32-row strip. Horizontal 5-sum per row from 1 float4 + 2 float2 halo loads;
// vertical 5-sum via sliding window in a 6-deep register ring (full unroll).
// Full-width rows make REFLECT_101 x-halo resolve inside the own float4.

#define IMG_H 512
#define IMG_W 512
#define NF4   (IMG_W / 4)      // 128 float4-columns per row
#define STRIP 32               // output rows per block
#define NSTRIPS (IMG_H / STRIP)

struct F4 { float x, y, z, w; };

__global__ __launch_bounds__(128) void smooth_box5_reg(
    const float* __restrict__ in, float* __restrict__ out)
{
    const int c4 = threadIdx.x;                // 0..127: this thread's float4-column
    const int r0 = blockIdx.x * STRIP;         // first output row of strip
    const size_t planeOff = (size_t)blockIdx.y * (IMG_H * IMG_W);
    const float* __restrict__ ip = in + planeOff;
    float*       __restrict__ op = out + planeOff;
    const int xb = c4 * 4;

    // Horizontal 5-sum of (reflected) row r for this thread's 4 columns.
    auto hrow = [&](int r) -> F4 {
        int ry = (r < 0) ? -r : r;                        // REFLECT_101 top
        ry = (ry >= IMG_H) ? (2 * IMG_H - 2 - ry) : ry;   // REFLECT_101 bottom
        const float* row = ip + (size_t)ry * IMG_W;
        const float4 b = *(const float4*)(row + xb);
        float a2, a3, cc0, cc1;
        if (c4 > 0) {                                     // cols xb-2, xb-1
            const float2 a = *(const float2*)(row + xb - 2);
            a2 = a.x; a3 = a.y;
        } else {                                          // reflect: -2->2, -1->1
            a2 = b.z; a3 = b.y;
        }
        if (c4 < NF4 - 1) {                               // cols xb+4, xb+5
            const float2 c = *(const float2*)(row + xb + 4);
            cc0 = c.x; cc1 = c.y;
        } else {                                          // reflect: 512->510, 513->509
            cc0 = b.z; cc1 = b.y;
        }
        const float s = b.x + b.y + b.z + b.w;
        F4 h;
        h.x = s - b.w + a2 + a3;   // b0+b1+b2 + a2+a3
        h.y = s + a3;              // a3+b0+b1+b2+b3
        h.z = s + cc0;             // b0+b1+b2+b3+c0
        h.w = s - b.x + cc0 + cc1; // b1+b2+b3 + c0+c1
        return h;
    };

    // Init vertical window over rows r0-2 .. r0+2.
    F4 h[6];
    h[0] = hrow(r0 - 2);
    h[1] = hrow(r0 - 1);
    h[2] = hrow(r0);
    h[3] = hrow(r0 + 1);
    h[4] = hrow(r0 + 2);
    F4 S;
    S.x = h[0].x + h[1].x + h[2].x + h[3].x + h[4].x;
    S.y = h[0].y + h[1].y + h[2].y + h[3].y + h[4].y;
    S.z = h[0].z + h[1].z + h[2].z + h[3].z + h[4].z;
    S.w = h[0].w + h[1].w + h[2].w + h[3].w + h[4].w;

    const float inv = 0.2f * 0.2f;   // matches reference's two 1/5 passes
    float* orow = op + (size_t)r0 * IMG_W + xb;

    #pragma unroll
    for (int rr = 0; rr < STRIP; ++rr) {
        float4 o;
        o.x = S.x * inv; o.y = S.y * inv; o.z = S.z * inv; o.w = S.w * inv;
        *(float4*)orow = o;
        orow += IMG_W;
        if (rr < STRIP - 1) {
            const int inew = (rr + 5) % 6;   // constant-folds under full unroll
            const int iold = rr % 6;
            h[inew] = hrow(r0 + rr + 3);
            S.x += h[inew].x - h[iold].x;
            S.y += h[inew].y - h[iold].y;
            S.z += h[inew].z - h[iold].z;
            S.w += h[inew].w - h[iold].w;
        }
    }
}

extern "C" void kernel_launch(void* const* d_in, const int* in_sizes, int n_in,
                              void* d_out, int out_size, void* d_ws, size_t ws_size,
                              hipStream_t stream) {
    const float* img = (const float*)d_in[0];
    float* out = (float*)d_out;
    const int BC = 32 * 3;                   // planes
    dim3 grid(NSTRIPS, BC);                  // 16 x 96 = 1536 blocks
    dim3 block(128);                         // 2 waves; 6 blocks/CU -> 12 waves/CU
    smooth_box5_reg<<<grid, block, 0, stream>>>(img, out);
}

// Round 3
// 202.455 us; speedup vs baseline: 1.0115x; 1.0115x over previous
//
#include <hip/hip_runtime.h>

// 5x5 normalized box blur, REFLECT_101, fp32, NCHW 32x3x512x512.
// Register-only separable blur, chunked loads for MLP:
// each thread owns one float4-column of a 32-row strip. Rows are loaded in
// batches of 8 (24 independent loads in flight) before consumption, then the
// horizontal 5-sum + vertical sliding-window sum run from registers.
// Halo loads are unconditional with clamped addresses (selects fix reflect),
// so the load batch has no exec-mask divergence to break clustering.

#define IMG_H 512
#define IMG_W 512
#define NF4   (IMG_W / 4)      // 128 float4-columns per row
#define STRIP 32               // output rows per block (halo amp 36/32 = 1.125x)
#define NSTRIPS (IMG_H / STRIP)

struct F4 { float x, y, z, w; };
struct Raw { float4 b; float2 a, c; };

__global__ __launch_bounds__(128) void smooth_box5_mlp(
    const float* __restrict__ in, float* __restrict__ out)
{
    const int c4 = threadIdx.x;                 // 0..127 float4-column
    const int r0 = blockIdx.x * STRIP;
    const size_t planeOff = (size_t)blockIdx.y * (IMG_H * IMG_W);
    const float* __restrict__ ip = in + planeOff;
    float*       __restrict__ op = out + planeOff;

    const int xb = c4 * 4;
    const bool left  = (c4 == 0);
    const bool right = (c4 == NF4 - 1);
    const int xa = left  ? 0          : xb - 2;   // clamped, 8B-aligned
    const int xc = right ? IMG_W - 8  : xb + 4;   // clamped, 8B-aligned

    // Raw load of (reflected) row r: 3 independent loads, no branches.
    auto load_raw = [&](int r) -> Raw {
        int ry = (r < 0) ? -r : r;                       // REFLECT_101 top
        ry = (ry >= IMG_H) ? (2 * IMG_H - 2 - ry) : ry;  // REFLECT_101 bottom
        const float* row = ip + (size_t)ry * IMG_W;
        Raw q;
        q.b = *(const float4*)(row + xb);
        q.a = *(const float2*)(row + xa);
        q.c = *(const float2*)(row + xc);
        return q;
    };

    // Horizontal 5-sum from a raw row (reflect fixes via selects).
    auto hcomp = [&](const Raw& q) -> F4 {
        const float a2 = left  ? q.b.z : q.a.x;   // col xb-2 (or reflect 2)
        const float a3 = left  ? q.b.y : q.a.y;   // col xb-1 (or reflect 1)
        const float c0 = right ? q.b.z : q.c.x;   // col xb+4 (or reflect 510)
        const float c1 = right ? q.b.y : q.c.y;   // col xb+5 (or reflect 509)
        const float s = q.b.x + q.b.y + q.b.z + q.b.w;
        F4 h;
        h.x = s - q.b.w + a2 + a3;
        h.y = s + a3;
        h.z = s + c0;
        h.w = s - q.b.x + c0 + c1;
        return h;
    };

    // ---- prologue: batch-load rows r0-2 .. r0+2 (15 loads in flight) ----
    Raw p[5];
    #pragma unroll
    for (int k = 0; k < 5; ++k) p[k] = load_raw(r0 - 2 + k);

    F4 h[6];
    #pragma unroll
    for (int k = 0; k < 5; ++k) h[k] = hcomp(p[k]);

    F4 S;
    S.x = h[0].x + h[1].x + h[2].x + h[3].x + h[4].x;
    S.y = h[0].y + h[1].y + h[2].y + h[3].y + h[4].y;
    S.z = h[0].z + h[1].z + h[2].z + h[3].z + h[4].z;
    S.w = h[0].w + h[1].w + h[2].w + h[3].w + h[4].w;

    const float inv = 0.2f * 0.2f;
    float* orow = op + (size_t)r0 * IMG_W + xb;

    // ---- main: 4 chunks of 8 output rows; batch 8 rows' loads per chunk ----
    #pragma unroll
    for (int j = 0; j < 4; ++j) {
        const int nload = (j < 3) ? 8 : 7;   // last output row needs no new row
        Raw q[8];
        #pragma unroll
        for (int k = 0; k < 8; ++k) {
            if (k < nload) q[k] = load_raw(r0 + 8 * j + 3 + k);
        }
        #pragma unroll
        for (int i = 0; i < 8; ++i) {
            const int rr = 8 * j + i;        // output row (0..31)
            float4 o;
            o.x = S.x * inv; o.y = S.y * inv; o.z = S.z * inv; o.w = S.w * inv;
            *(float4*)orow = o;
            orow += IMG_W;
            if (rr < STRIP - 1) {
                const int inew = (rr + 5) % 6;   // compile-time under unroll
                const int iold = rr % 6;
                h[inew] = hcomp(q[i]);
                S.x += h[inew].x - h[iold].x;
                S.y += h[inew].y - h[iold].y;
                S.z += h[inew].z - h[iold].z;
                S.w += h[inew].w - h[iold].w;
            }
        }
    }
}

extern "C" void kernel_launch(void* const* d_in, const int* in_sizes, int n_in,
                              void* d_out, int out_size, void* d_ws, size_t ws_size,
                              hipStream_t stream) {
    const float* img = (const float*)d_in[0];
    float* out = (float*)d_out;
    const int BC = 32 * 3;                   // planes
    dim3 grid(NSTRIPS, BC);                  // 16 x 96 = 1536 blocks
    dim3 block(128);
    smooth_box5_mlp<<<grid, block, 0, stream>>>(img, out);
}